// Round 2
// 1042.545 us; speedup vs baseline: 1.3740x; 1.3740x over previous
//
#include <hip/hip_runtime.h>
#include <math.h>

#define NN 100000
#define NE 3200000
#define D 64
#define H 4096
#define H3 12288

#define NBKT 782        // ceil(NN/128): buckets of 128 dst nodes (bucket = dst>>7)
#define NBKTP 784       // padded to multiple of 4 for the partition scan
#define PCHUNK 4096     // edges per partition block
#define NPART 782       // ceil(NE/PCHUNK)
#define CAP 8192        // LDS stage per bucket; counts ~ Binom(3.2M,1.28e-4): mean 4096, sd 64 -> +64 sigma

// ---------------- pass 1: bucket histogram (dst>>7) + out-degree atomics ----------------
__global__ __launch_bounds__(256) void hist_kernel(const int* __restrict__ src,
                                                   const int* __restrict__ dst,
                                                   int* __restrict__ outcnt,
                                                   int* __restrict__ bucketCnt) {
    __shared__ int h[NBKT];
    for (int i = threadIdx.x; i < NBKT; i += 256) h[i] = 0;
    __syncthreads();
    int stride = gridDim.x * 256;
    for (int e = blockIdx.x * 256 + threadIdx.x; e < NE; e += stride) {
        int d = dst[e];
        atomicAdd(&h[d >> 7], 1);
        atomicAdd(&outcnt[src[e]], 1);   // out-degree (in-degree comes free from bucket_csr)
    }
    __syncthreads();
    for (int i = threadIdx.x; i < NBKT; i += 256)
        if (h[i]) atomicAdd(&bucketCnt[i], h[i]);
}

// ---------------- pass 2: scan bucket counts -> bucketPtr, bucketCur ----------------
__global__ __launch_bounds__(1024) void bucket_scan(const int* __restrict__ bucketCnt,
                                                    int* __restrict__ bucketPtr,
                                                    int* __restrict__ bucketCur,
                                                    int* __restrict__ rowptr) {
    __shared__ int s[1024];
    int t = threadIdx.x;
    int v = (t < NBKT) ? bucketCnt[t] : 0;
    s[t] = v;
    __syncthreads();
    for (int off = 1; off < 1024; off <<= 1) {
        int u = (t >= off) ? s[t - off] : 0;
        __syncthreads();
        s[t] += u;
        __syncthreads();
    }
    int excl = s[t] - v;
    if (t < NBKT) { bucketPtr[t] = excl; bucketCur[t] = excl; }
    if (t == 0)   { bucketPtr[NBKT] = NE; rowptr[NN] = NE; }
}

// ---------------- pass 3: partition edges into bucket-contiguous packed records ----------------
// record = (src << 7) | (dst & 127)   (17 + 7 = 24 bits)
__global__ __launch_bounds__(256) void partition_kernel(const int* __restrict__ src,
                                                        const int* __restrict__ dst,
                                                        int* __restrict__ bucketCur,
                                                        int* __restrict__ recs) {
    __shared__ int h[NBKTP];           // per-bucket counts for this chunk
    __shared__ int st[NBKTP];          // exclusive starts, then staging cursor
    __shared__ int shf[NBKTP];         // global_base - local_start
    __shared__ int ss[256];            // block scan
    __shared__ unsigned stage[PCHUNK];
    __shared__ unsigned short bos[PCHUNK];

    int t = threadIdx.x;
    for (int i = t; i < NBKTP; i += 256) h[i] = 0;
    __syncthreads();

    int e0 = blockIdx.x * PCHUNK;
    int n = NE - e0; if (n > PCHUNK) n = PCHUNK;

    for (int i = t; i < n; i += 256) atomicAdd(&h[dst[e0 + i] >> 7], 1);
    __syncthreads();

    // exclusive scan of 784 bins: thread t owns bins [4t, 4t+4)
    int c0 = 0, c1 = 0, c2 = 0, c3 = 0, sum = 0;
    int b4 = t * 4;
    if (b4 < NBKTP)     { c0 = h[b4];     sum += c0; }
    if (b4 + 1 < NBKTP) { c1 = h[b4 + 1]; sum += c1; }
    if (b4 + 2 < NBKTP) { c2 = h[b4 + 2]; sum += c2; }
    if (b4 + 3 < NBKTP) { c3 = h[b4 + 3]; sum += c3; }
    ss[t] = sum;
    __syncthreads();
    for (int off = 1; off < 256; off <<= 1) {
        int u = (t >= off) ? ss[t - off] : 0;
        __syncthreads();
        ss[t] += u;
        __syncthreads();
    }
    int run = ss[t] - sum;  // exclusive base for this thread's bins
    if (b4 < NBKTP)     { st[b4]     = run; run += c0; }
    if (b4 + 1 < NBKTP) { st[b4 + 1] = run; run += c1; }
    if (b4 + 2 < NBKTP) { st[b4 + 2] = run; run += c2; }
    if (b4 + 3 < NBKTP) { st[b4 + 3] = run; run += c3; }
    __syncthreads();

    // reserve global space per bucket
    for (int b = t; b < NBKT; b += 256) {
        int cc = h[b];
        if (cc) {
            int g = atomicAdd(&bucketCur[b], cc);
            shf[b] = g - st[b];
        }
    }
    __syncthreads();

    // stage records ordered by bucket (st doubles as cursor)
    for (int i = t; i < n; i += 256) {
        int d = dst[e0 + i];
        int b = d >> 7;
        int slot = atomicAdd(&st[b], 1);
        stage[slot] = ((unsigned)src[e0 + i] << 7) | (unsigned)(d & 127);
        bos[slot] = (unsigned short)b;
    }
    __syncthreads();

    // coalesced flush: bucket-contiguous chunks
    for (int s2 = t; s2 < n; s2 += 256)
        recs[shf[bos[s2]] + s2] = (int)stage[s2];
}

// ---------------- pass 4: per-bucket CSR finalize (in-place), rowptr + in_norm ----------------
__global__ __launch_bounds__(256) void bucket_csr(int* __restrict__ recs,
                                                  const int* __restrict__ bucketPtr,
                                                  int* __restrict__ rowptr,
                                                  float* __restrict__ innorm) {
    __shared__ int h[128];
    __shared__ int pex[128];
    __shared__ int stageS[CAP];
    int b = blockIdx.x, t = threadIdx.x;
    int p0 = bucketPtr[b], p1 = bucketPtr[b + 1];
    int cnt = p1 - p0;
    if (cnt > CAP) cnt = CAP;  // defensive: statistically impossible, prevents LDS OOB
    if (t < 128) h[t] = 0;
    __syncthreads();

    // load records to LDS + local node histogram
    for (int i = t; i < cnt; i += 256) {
        int r = recs[p0 + i];
        stageS[i] = r;
        atomicAdd(&h[r & 127], 1);
    }
    __syncthreads();

    if (t < 128) pex[t] = h[t];
    __syncthreads();
    for (int off = 1; off < 128; off <<= 1) {
        int u = 0;
        if (t < 128 && t >= off) u = pex[t - off];
        __syncthreads();
        if (t < 128) pex[t] += u;
        __syncthreads();
    }
    if (t < 128) {
        int ex = pex[t] - h[t];
        int node = b * 128 + t;
        if (node < NN) {
            rowptr[node] = p0 + ex;
            innorm[node] = rsqrtf(fmaxf((float)h[t], 1.0f));
        }
        pex[t] = ex;  // becomes scatter cursor
    }
    __syncthreads();

    // scatter src back in-place: dense 16KB window, L2-absorbed full-line evictions
    for (int i = t; i < cnt; i += 256) {
        int r = stageS[i];
        int slot = atomicAdd(&pex[r & 127], 1);
        recs[p0 + slot] = r >> 7;
    }
}

// ---------------- out-norm ----------------
__global__ __launch_bounds__(256) void outnorm_kernel(const int* __restrict__ outcnt,
                                                      float* __restrict__ outn) {
    int i = blockIdx.x * 256 + threadIdx.x;
    if (i < NN) outn[i] = rsqrtf(fmaxf((float)outcnt[i], 1.0f));
}

// ---------------- GRU: fused matvec for both cells ----------------
__global__ __launch_bounds__(256) void gru_matvec(
    const float* __restrict__ Wih, const float* __restrict__ Whh,
    const float* __restrict__ bih, const float* __restrict__ bhh,
    const float* __restrict__ pg1, const float* __restrict__ pg2,
    const float* __restrict__ g1w, const float* __restrict__ g2w,
    float* __restrict__ gi1, float* __restrict__ gh1,
    float* __restrict__ gi2, float* __restrict__ gh2) {
    int r = blockIdx.x;
    int tid = threadIdx.x;
    const float4* wi = (const float4*)(Wih + (size_t)r * H);
    const float4* wh = (const float4*)(Whh + (size_t)r * H);
    const float4* x1 = (const float4*)pg1;
    const float4* x2 = (const float4*)pg2;
    const float4* h1 = (const float4*)g1w;
    const float4* h2 = (const float4*)g2w;
    float a0 = 0.f, a1 = 0.f, a2 = 0.f, a3 = 0.f;
    for (int k = tid; k < H / 4; k += 256) {
        float4 wiv = wi[k];
        float4 whv = wh[k];
        float4 v1 = x1[k], v2 = x2[k], u1 = h1[k], u2 = h2[k];
        a0 += wiv.x * v1.x + wiv.y * v1.y + wiv.z * v1.z + wiv.w * v1.w;
        a1 += whv.x * u1.x + whv.y * u1.y + whv.z * u1.z + whv.w * u1.w;
        a2 += wiv.x * v2.x + wiv.y * v2.y + wiv.z * v2.z + wiv.w * v2.w;
        a3 += whv.x * u2.x + whv.y * u2.y + whv.z * u2.z + whv.w * u2.w;
    }
    for (int off = 32; off; off >>= 1) {
        a0 += __shfl_down(a0, off);
        a1 += __shfl_down(a1, off);
        a2 += __shfl_down(a2, off);
        a3 += __shfl_down(a3, off);
    }
    __shared__ float red[4][4];
    int wv = tid >> 6;
    if ((tid & 63) == 0) {
        red[wv][0] = a0; red[wv][1] = a1; red[wv][2] = a2; red[wv][3] = a3;
    }
    __syncthreads();
    if (tid < 4) {
        float s = red[0][tid] + red[1][tid] + red[2][tid] + red[3][tid];
        if (tid == 0)      gi1[r] = s + bih[r];
        else if (tid == 1) gh1[r] = s + bhh[r];
        else if (tid == 2) gi2[r] = s + bih[r];
        else               gh2[r] = s + bhh[r];
    }
}

__global__ __launch_bounds__(256) void gru_combine(
    const float* __restrict__ gi1, const float* __restrict__ gh1,
    const float* __restrict__ gi2, const float* __restrict__ gh2,
    const float* __restrict__ g1w, const float* __restrict__ g2w,
    float* __restrict__ w1, float* __restrict__ w2) {
    int gid = blockIdx.x * 256 + threadIdx.x;
    if (gid >= 2 * H) return;
    int c = gid >> 12;
    int j = gid & (H - 1);
    const float* gi = c ? gi2 : gi1;
    const float* gh = c ? gh2 : gh1;
    float hprev = c ? g2w[j] : g1w[j];
    float r = 1.f / (1.f + expf(-(gi[j] + gh[j])));
    float z = 1.f / (1.f + expf(-(gi[H + j] + gh[H + j])));
    float n = tanhf(gi[2 * H + j] + r * gh[2 * H + j]);
    float w = (1.f - z) * n + z * hprev;
    (c ? w2 : w1)[j] = w;
}

// ---------------- fused CSR aggregation + 64x64 GEMM (both layers) ----------------
// one wave per dst node; lane j owns feature column j
__global__ __launch_bounds__(256) void agg_gemm_fused(
    const int* __restrict__ rowptr, const int* __restrict__ csr_src,
    const float* __restrict__ x, const float* __restrict__ outn,
    const float* __restrict__ innorm, const float* __restrict__ W,
    const float* __restrict__ bias, float* __restrict__ out, int relu) {
    __shared__ float sW[D * D];
    int tid = threadIdx.x;
    for (int i = tid; i < D * D; i += 256) sW[i] = W[i];
    __syncthreads();
    int node = blockIdx.x * 4 + (tid >> 6);
    int lane = tid & 63;
    if (node >= NN) return;
    int e = rowptr[node], end = rowptr[node + 1];
    float acc = 0.f;
    for (; e + 3 < end; e += 4) {
        int s0 = csr_src[e], s1 = csr_src[e + 1];
        int s2 = csr_src[e + 2], s3 = csr_src[e + 3];
        float on0 = outn[s0], on1 = outn[s1], on2 = outn[s2], on3 = outn[s3];
        float v0 = x[(size_t)s0 * D + lane];
        float v1 = x[(size_t)s1 * D + lane];
        float v2 = x[(size_t)s2 * D + lane];
        float v3 = x[(size_t)s3 * D + lane];
        acc += v0 * on0 + v1 * on1 + v2 * on2 + v3 * on3;
    }
    for (; e < end; ++e) {
        int s0 = csr_src[e];
        acc += x[(size_t)s0 * D + lane] * outn[s0];
    }
    acc *= innorm[node];
    float o = 0.f;
#pragma unroll
    for (int k = 0; k < D; ++k) {
        float ak = __shfl(acc, k);
        o += ak * sW[k * D + lane];
    }
    o += bias[lane];
    if (relu) o = fmaxf(o, 0.f);
    out[(size_t)node * D + lane] = o;
}

extern "C" void kernel_launch(void* const* d_in, const int* in_sizes, int n_in,
                              void* d_out, int out_size, void* d_ws, size_t ws_size,
                              hipStream_t stream) {
    const float* x0   = (const float*)d_in[0];
    const float* gc1w = (const float*)d_in[1];
    const float* gc2w = (const float*)d_in[2];
    const float* gc1b = (const float*)d_in[3];
    const float* gc2b = (const float*)d_in[4];
    const float* pg1  = (const float*)d_in[5];
    const float* pg2  = (const float*)d_in[6];
    const float* Wih  = (const float*)d_in[7];
    const float* Whh  = (const float*)d_in[8];
    const float* bih  = (const float*)d_in[9];
    const float* bhh  = (const float*)d_in[10];
    const int*   src  = (const int*)d_in[11];
    const int*   dst  = (const int*)d_in[12];
    float* out = (float*)d_out;
    float* ws  = (float*)d_ws;

    // workspace layout (float offsets)
    float* outn     = ws;                       // 100000
    float* innorm   = ws + 100000;              // 100000
    int* outcnt     = (int*)(ws + 200000);      // 100000
    int* bucketCnt  = (int*)(ws + 300000);      // 1024 (pad)
    int* bucketPtr  = (int*)(ws + 301024);      // 1024 (pad, need NBKT+1)
    int* bucketCur  = (int*)(ws + 302048);      // 1024 (pad)
    int* rowptr     = (int*)(ws + 303072);      // 100001 -> pad to 100032
    float* w1  = ws + 403104;                   // H
    float* w2  = ws + 407200;                   // H
    float* gi1 = ws + 411296;                   // 3H
    float* gh1 = ws + 423584;                   // 3H
    float* gi2 = ws + 435872;                   // 3H
    float* gh2 = ws + 448160;                   // 3H
    int* csr   = (int*)(ws + 460448);           // NE (records, then in-place csr_src)
    float* h1w = ws + 3660448;                  // NN*D (layer-1 output)

    // zero outcnt + bucketCnt in one shot
    hipMemsetAsync(outcnt, 0, (size_t)(100000 + 1024) * sizeof(int), stream);

    // CSR build via bucketed counting sort
    hist_kernel<<<2048, 256, 0, stream>>>(src, dst, outcnt, bucketCnt);
    bucket_scan<<<1, 1024, 0, stream>>>(bucketCnt, bucketPtr, bucketCur, rowptr);
    partition_kernel<<<NPART, 256, 0, stream>>>(src, dst, bucketCur, csr);
    bucket_csr<<<NBKT, 256, 0, stream>>>(csr, bucketPtr, rowptr, innorm);
    outnorm_kernel<<<(NN + 255) / 256, 256, 0, stream>>>(outcnt, outn);

    // GRU weight evolution (both cells fused)
    gru_matvec<<<H3, 256, 0, stream>>>(Wih, Whh, bih, bhh, pg1, pg2, gc1w, gc2w,
                                       gi1, gh1, gi2, gh2);
    gru_combine<<<(2 * H + 255) / 256, 256, 0, stream>>>(gi1, gh1, gi2, gh2,
                                                         gc1w, gc2w, w1, w2);

    // layer 1: fused aggregation + GEMM + relu -> h1w
    agg_gemm_fused<<<(NN + 3) / 4, 256, 0, stream>>>(rowptr, csr, x0, outn,
                                                     innorm, w1, gc1b, h1w, 1);
    // layer 2: fused aggregation + GEMM -> out
    agg_gemm_fused<<<(NN + 3) / 4, 256, 0, stream>>>(rowptr, csr, h1w, outn,
                                                     innorm, w2, gc2b, out, 0);
}

// Round 3
// 998.494 us; speedup vs baseline: 1.4346x; 1.0441x over previous
//
#include <hip/hip_runtime.h>
#include <math.h>

#define NN 100000
#define NE 3200000
#define D 64
#define H 4096
#define H3 12288

#define NBKT 782        // ceil(NN/128): buckets of 128 dst nodes (bucket = dst>>7)
#define NBKTP 784       // padded to multiple of 4 for the partition scan
#define PCHUNK 4096     // edges per partition block
#define NPART 782       // ceil(NE/PCHUNK)
#define CAP 8192        // LDS stage per bucket; counts ~ Binom(3.2M,1.28e-4): mean 4096, sd 64 -> +64 sigma

// ---------------- pass 1: bucket histogram (dst>>7) only ----------------
__global__ __launch_bounds__(256) void hist_kernel(const int* __restrict__ dst,
                                                   int* __restrict__ bucketCnt) {
    __shared__ int h[NBKT];
    for (int i = threadIdx.x; i < NBKT; i += 256) h[i] = 0;
    __syncthreads();
    int stride = gridDim.x * 256;
    for (int e = blockIdx.x * 256 + threadIdx.x; e < NE; e += stride)
        atomicAdd(&h[dst[e] >> 7], 1);
    __syncthreads();
    for (int i = threadIdx.x; i < NBKT; i += 256)
        if (h[i]) atomicAdd(&bucketCnt[i], h[i]);
}

// ---------------- pass 2: scan bucket counts -> bucketPtr, bucketCur ----------------
__global__ __launch_bounds__(1024) void bucket_scan(const int* __restrict__ bucketCnt,
                                                    int* __restrict__ bucketPtr,
                                                    int* __restrict__ bucketCur,
                                                    int* __restrict__ rowptr) {
    __shared__ int s[1024];
    int t = threadIdx.x;
    int v = (t < NBKT) ? bucketCnt[t] : 0;
    s[t] = v;
    __syncthreads();
    for (int off = 1; off < 1024; off <<= 1) {
        int u = (t >= off) ? s[t - off] : 0;
        __syncthreads();
        s[t] += u;
        __syncthreads();
    }
    int excl = s[t] - v;
    if (t < NBKT) { bucketPtr[t] = excl; bucketCur[t] = excl; }
    if (t == 0)   { bucketPtr[NBKT] = NE; rowptr[NN] = NE; }
}

// ---------------- pass 3: partition edges into bucket-contiguous packed records ----------------
// record = (src << 7) | (dst & 127); also accumulates out-degree atomics (src is read here anyway)
__global__ __launch_bounds__(256) void partition_kernel(const int* __restrict__ src,
                                                        const int* __restrict__ dst,
                                                        int* __restrict__ bucketCur,
                                                        int* __restrict__ outcnt,
                                                        int* __restrict__ recs) {
    __shared__ int h[NBKTP];           // per-bucket counts for this chunk
    __shared__ int st[NBKTP];          // exclusive starts, then staging cursor
    __shared__ int shf[NBKTP];         // global_base - local_start
    __shared__ int ss[256];            // block scan
    __shared__ unsigned stage[PCHUNK];
    __shared__ unsigned short bos[PCHUNK];

    int t = threadIdx.x;
    for (int i = t; i < NBKTP; i += 256) h[i] = 0;
    __syncthreads();

    int e0 = blockIdx.x * PCHUNK;
    int n = NE - e0; if (n > PCHUNK) n = PCHUNK;

    for (int i = t; i < n; i += 256) {
        atomicAdd(&h[dst[e0 + i] >> 7], 1);
        atomicAdd(&outcnt[src[e0 + i]], 1);   // out-degree, latency hidden under LDS work
    }
    __syncthreads();

    // exclusive scan of 784 bins: thread t owns bins [4t, 4t+4)
    int c0 = 0, c1 = 0, c2 = 0, c3 = 0, sum = 0;
    int b4 = t * 4;
    if (b4 < NBKTP)     { c0 = h[b4];     sum += c0; }
    if (b4 + 1 < NBKTP) { c1 = h[b4 + 1]; sum += c1; }
    if (b4 + 2 < NBKTP) { c2 = h[b4 + 2]; sum += c2; }
    if (b4 + 3 < NBKTP) { c3 = h[b4 + 3]; sum += c3; }
    ss[t] = sum;
    __syncthreads();
    for (int off = 1; off < 256; off <<= 1) {
        int u = (t >= off) ? ss[t - off] : 0;
        __syncthreads();
        ss[t] += u;
        __syncthreads();
    }
    int run = ss[t] - sum;  // exclusive base for this thread's bins
    if (b4 < NBKTP)     { st[b4]     = run; run += c0; }
    if (b4 + 1 < NBKTP) { st[b4 + 1] = run; run += c1; }
    if (b4 + 2 < NBKTP) { st[b4 + 2] = run; run += c2; }
    if (b4 + 3 < NBKTP) { st[b4 + 3] = run; run += c3; }
    __syncthreads();

    // reserve global space per bucket
    for (int b = t; b < NBKT; b += 256) {
        int cc = h[b];
        if (cc) {
            int g = atomicAdd(&bucketCur[b], cc);
            shf[b] = g - st[b];
        }
    }
    __syncthreads();

    // stage records ordered by bucket (st doubles as cursor)
    for (int i = t; i < n; i += 256) {
        int d = dst[e0 + i];
        int b = d >> 7;
        int slot = atomicAdd(&st[b], 1);
        stage[slot] = ((unsigned)src[e0 + i] << 7) | (unsigned)(d & 127);
        bos[slot] = (unsigned short)b;
    }
    __syncthreads();

    // coalesced flush: bucket-contiguous chunks
    for (int s2 = t; s2 < n; s2 += 256)
        recs[shf[bos[s2]] + s2] = (int)stage[s2];
}

// ---------------- pass 4: per-bucket CSR finalize (in-place), rowptr + in_norm + out_norm ----------------
__global__ __launch_bounds__(256) void bucket_csr(int* __restrict__ recs,
                                                  const int* __restrict__ bucketPtr,
                                                  const int* __restrict__ outcnt,
                                                  int* __restrict__ rowptr,
                                                  float* __restrict__ innorm,
                                                  float* __restrict__ outn) {
    __shared__ int h[128];
    __shared__ int pex[128];
    __shared__ int stageS[CAP];
    int b = blockIdx.x, t = threadIdx.x;
    int p0 = bucketPtr[b], p1 = bucketPtr[b + 1];
    int cnt = p1 - p0;
    if (cnt > CAP) cnt = CAP;  // defensive: statistically impossible, prevents LDS OOB
    if (t < 128) h[t] = 0;
    __syncthreads();

    // load records to LDS + local node histogram
    for (int i = t; i < cnt; i += 256) {
        int r = recs[p0 + i];
        stageS[i] = r;
        atomicAdd(&h[r & 127], 1);
    }
    __syncthreads();

    if (t < 128) pex[t] = h[t];
    __syncthreads();
    for (int off = 1; off < 128; off <<= 1) {
        int u = 0;
        if (t < 128 && t >= off) u = pex[t - off];
        __syncthreads();
        if (t < 128) pex[t] += u;
        __syncthreads();
    }
    if (t < 128) {
        int ex = pex[t] - h[t];
        int node = b * 128 + t;
        if (node < NN) {
            rowptr[node] = p0 + ex;
            innorm[node] = rsqrtf(fmaxf((float)h[t], 1.0f));
            outn[node]   = rsqrtf(fmaxf((float)outcnt[node], 1.0f));
        }
        pex[t] = ex;  // becomes scatter cursor
    }
    __syncthreads();

    // scatter src back in-place: dense 16KB window, L2-absorbed full-line evictions
    for (int i = t; i < cnt; i += 256) {
        int r = stageS[i];
        int slot = atomicAdd(&pex[r & 127], 1);
        recs[p0 + slot] = r >> 7;
    }
}

// ---------------- GRU: fused matvec for both cells ----------------
__global__ __launch_bounds__(256) void gru_matvec(
    const float* __restrict__ Wih, const float* __restrict__ Whh,
    const float* __restrict__ bih, const float* __restrict__ bhh,
    const float* __restrict__ pg1, const float* __restrict__ pg2,
    const float* __restrict__ g1w, const float* __restrict__ g2w,
    float* __restrict__ gi1, float* __restrict__ gh1,
    float* __restrict__ gi2, float* __restrict__ gh2) {
    int r = blockIdx.x;
    int tid = threadIdx.x;
    const float4* wi = (const float4*)(Wih + (size_t)r * H);
    const float4* wh = (const float4*)(Whh + (size_t)r * H);
    const float4* x1 = (const float4*)pg1;
    const float4* x2 = (const float4*)pg2;
    const float4* h1 = (const float4*)g1w;
    const float4* h2 = (const float4*)g2w;
    float a0 = 0.f, a1 = 0.f, a2 = 0.f, a3 = 0.f;
    for (int k = tid; k < H / 4; k += 256) {
        float4 wiv = wi[k];
        float4 whv = wh[k];
        float4 v1 = x1[k], v2 = x2[k], u1 = h1[k], u2 = h2[k];
        a0 += wiv.x * v1.x + wiv.y * v1.y + wiv.z * v1.z + wiv.w * v1.w;
        a1 += whv.x * u1.x + whv.y * u1.y + whv.z * u1.z + whv.w * u1.w;
        a2 += wiv.x * v2.x + wiv.y * v2.y + wiv.z * v2.z + wiv.w * v2.w;
        a3 += whv.x * u2.x + whv.y * u2.y + whv.z * u2.z + whv.w * u2.w;
    }
    for (int off = 32; off; off >>= 1) {
        a0 += __shfl_down(a0, off);
        a1 += __shfl_down(a1, off);
        a2 += __shfl_down(a2, off);
        a3 += __shfl_down(a3, off);
    }
    __shared__ float red[4][4];
    int wv = tid >> 6;
    if ((tid & 63) == 0) {
        red[wv][0] = a0; red[wv][1] = a1; red[wv][2] = a2; red[wv][3] = a3;
    }
    __syncthreads();
    if (tid < 4) {
        float s = red[0][tid] + red[1][tid] + red[2][tid] + red[3][tid];
        if (tid == 0)      gi1[r] = s + bih[r];
        else if (tid == 1) gh1[r] = s + bhh[r];
        else if (tid == 2) gi2[r] = s + bih[r];
        else               gh2[r] = s + bhh[r];
    }
}

__global__ __launch_bounds__(256) void gru_combine(
    const float* __restrict__ gi1, const float* __restrict__ gh1,
    const float* __restrict__ gi2, const float* __restrict__ gh2,
    const float* __restrict__ g1w, const float* __restrict__ g2w,
    float* __restrict__ w1, float* __restrict__ w2) {
    int gid = blockIdx.x * 256 + threadIdx.x;
    if (gid >= 2 * H) return;
    int c = gid >> 12;
    int j = gid & (H - 1);
    const float* gi = c ? gi2 : gi1;
    const float* gh = c ? gh2 : gh1;
    float hprev = c ? g2w[j] : g1w[j];
    float r = 1.f / (1.f + expf(-(gi[j] + gh[j])));
    float z = 1.f / (1.f + expf(-(gi[H + j] + gh[H + j])));
    float n = tanhf(gi[2 * H + j] + r * gh[2 * H + j]);
    float w = (1.f - z) * n + z * hprev;
    (c ? w2 : w1)[j] = w;
}

// ---------------- fused CSR aggregation + 64x64 GEMM (both layers) ----------------
// one wave per dst node; lane j owns feature column j.
// MLP restructure: coalesced 64-wide index/outn preload, shfl-broadcast, 8-deep row gathers.
// USE_ON=1: per-edge outn scaling (layer 1, raw x input). USE_ON=0: input pre-scaled (layer 2).
// outn_next != nullptr: output is pre-scaled by outn[node] for the NEXT layer's aggregation.
template <int USE_ON>
__global__ __launch_bounds__(256) void agg_gemm_fused(
    const int* __restrict__ rowptr, const int* __restrict__ csr_src,
    const float* __restrict__ x, const float* __restrict__ outn,
    const float* __restrict__ innorm, const float* __restrict__ W,
    const float* __restrict__ bias, const float* __restrict__ outn_next,
    float* __restrict__ out, int relu) {
    __shared__ float sW[D * D];
    int tid = threadIdx.x;
    for (int i = tid; i < D * D; i += 256) sW[i] = W[i];
    __syncthreads();
    int node = blockIdx.x * 4 + (tid >> 6);
    int lane = tid & 63;
    if (node >= NN) return;
    int e0 = rowptr[node], e1 = rowptr[node + 1];
    float acc = 0.f;
    for (int base = e0; base < e1; base += 64) {
        int nk = e1 - base; if (nk > 64) nk = 64;
        int m = base + lane;
        int idxv = (m < e1) ? csr_src[m] : 0;          // coalesced 64-wide index load
        float onv = 0.f;
        if (USE_ON) onv = (m < e1) ? outn[idxv] : 0.f; // 64 parallel random gathers, all in flight
        int k = 0;
        for (; k + 8 <= nk; k += 8) {
            int ss[8]; float oo[8]; float vv[8];
#pragma unroll
            for (int u = 0; u < 8; ++u) {
                ss[u] = __shfl(idxv, k + u);
                if (USE_ON) oo[u] = __shfl(onv, k + u);
            }
#pragma unroll
            for (int u = 0; u < 8; ++u)
                vv[u] = x[(size_t)ss[u] * D + lane];   // 8 independent 256B row gathers
#pragma unroll
            for (int u = 0; u < 8; ++u)
                acc += USE_ON ? vv[u] * oo[u] : vv[u];
        }
        for (; k < nk; ++k) {
            int s = __shfl(idxv, k);
            float v = x[(size_t)s * D + lane];
            acc += USE_ON ? v * __shfl(onv, k) : v;
        }
    }
    acc *= innorm[node];
    float o = 0.f;
#pragma unroll
    for (int kk = 0; kk < D; ++kk) {
        float ak = __shfl(acc, kk);
        o += ak * sW[kk * D + lane];
    }
    o += bias[lane];
    if (relu) o = fmaxf(o, 0.f);
    if (outn_next) o *= outn_next[node];   // pre-scale for next layer's gather
    out[(size_t)node * D + lane] = o;
}

extern "C" void kernel_launch(void* const* d_in, const int* in_sizes, int n_in,
                              void* d_out, int out_size, void* d_ws, size_t ws_size,
                              hipStream_t stream) {
    const float* x0   = (const float*)d_in[0];
    const float* gc1w = (const float*)d_in[1];
    const float* gc2w = (const float*)d_in[2];
    const float* gc1b = (const float*)d_in[3];
    const float* gc2b = (const float*)d_in[4];
    const float* pg1  = (const float*)d_in[5];
    const float* pg2  = (const float*)d_in[6];
    const float* Wih  = (const float*)d_in[7];
    const float* Whh  = (const float*)d_in[8];
    const float* bih  = (const float*)d_in[9];
    const float* bhh  = (const float*)d_in[10];
    const int*   src  = (const int*)d_in[11];
    const int*   dst  = (const int*)d_in[12];
    float* out = (float*)d_out;
    float* ws  = (float*)d_ws;

    // workspace layout (float offsets)
    float* outn     = ws;                       // 100000
    float* innorm   = ws + 100000;              // 100000
    int* outcnt     = (int*)(ws + 200000);      // 100000
    int* bucketCnt  = (int*)(ws + 300000);      // 1024 (pad)
    int* bucketPtr  = (int*)(ws + 301024);      // 1024 (pad, need NBKT+1)
    int* bucketCur  = (int*)(ws + 302048);      // 1024 (pad)
    int* rowptr     = (int*)(ws + 303072);      // 100001 -> pad to 100032
    float* w1  = ws + 403104;                   // H
    float* w2  = ws + 407200;                   // H
    float* gi1 = ws + 411296;                   // 3H
    float* gh1 = ws + 423584;                   // 3H
    float* gi2 = ws + 435872;                   // 3H
    float* gh2 = ws + 448160;                   // 3H
    int* csr   = (int*)(ws + 460448);           // NE (records, then in-place csr_src)
    float* h1s = ws + 3660448;                  // NN*D (layer-1 output, pre-scaled by outn)

    // zero outcnt + bucketCnt in one shot
    hipMemsetAsync(outcnt, 0, (size_t)(100000 + 1024) * sizeof(int), stream);

    // CSR build via bucketed counting sort
    hist_kernel<<<2048, 256, 0, stream>>>(dst, bucketCnt);
    bucket_scan<<<1, 1024, 0, stream>>>(bucketCnt, bucketPtr, bucketCur, rowptr);
    partition_kernel<<<NPART, 256, 0, stream>>>(src, dst, bucketCur, outcnt, csr);
    bucket_csr<<<NBKT, 256, 0, stream>>>(csr, bucketPtr, outcnt, rowptr, innorm, outn);

    // GRU weight evolution (both cells fused)
    gru_matvec<<<H3, 256, 0, stream>>>(Wih, Whh, bih, bhh, pg1, pg2, gc1w, gc2w,
                                       gi1, gh1, gi2, gh2);
    gru_combine<<<(2 * H + 255) / 256, 256, 0, stream>>>(gi1, gh1, gi2, gh2,
                                                         gc1w, gc2w, w1, w2);

    // layer 1: aggregation (per-edge outn) + GEMM + relu, output pre-scaled by outn -> h1s
    agg_gemm_fused<1><<<(NN + 3) / 4, 256, 0, stream>>>(rowptr, csr, x0, outn,
                                                        innorm, w1, gc1b, outn, h1s, 1);
    // layer 2: aggregation (input already scaled) + GEMM -> out (unscaled, final)
    agg_gemm_fused<0><<<(NN + 3) / 4, 256, 0, stream>>>(rowptr, csr, h1s, outn,
                                                        innorm, w2, gc2b, nullptr, out, 0);
}